// Round 4
// baseline (2345.851 us; speedup 1.0000x reference)
//
#include <hip/hip_runtime.h>
#include <cmath>

constexpr int NN  = 100000;
constexpr int FIN = 128;
constexpr int HH  = 64;
constexpr int NE  = 3200000;
constexpr int NB  = (NN + 255) / 256;  // 391 scan blocks

// deg[col[e]] += 1  (4 edges/thread; NE % 4 == 0)
__global__ void k_count(const int* __restrict__ col, int* __restrict__ deg) {
    int e4 = blockIdx.x * blockDim.x + threadIdx.x;
    if (e4 * 4 < NE) {
        int4 c = ((const int4*)col)[e4];
        atomicAdd(&deg[c.x], 1);
        atomicAdd(&deg[c.y], 1);
        atomicAdd(&deg[c.z], 1);
        atomicAdd(&deg[c.w], 1);
    }
}

// dis[i] = rsqrt(deg[i] + 1)
__global__ void k_dis(const int* __restrict__ deg, float* __restrict__ dis) {
    int i = blockIdx.x * blockDim.x + threadIdx.x;
    if (i < NN) dis[i] = rsqrtf((float)(deg[i] + 1));
}

// per-256-chunk sums of deg
__global__ void k_bsum(const int* __restrict__ deg, int* __restrict__ bsum) {
    __shared__ int s[256];
    int i = blockIdx.x * 256 + threadIdx.x;
    s[threadIdx.x] = (i < NN) ? deg[i] : 0;
    __syncthreads();
    for (int off = 128; off > 0; off >>= 1) {
        if (threadIdx.x < off) s[threadIdx.x] += s[threadIdx.x + off];
        __syncthreads();
    }
    if (threadIdx.x == 0) bsum[blockIdx.x] = s[0];
}

// exclusive scan of the NB block sums (single block, Hillis-Steele over 512)
__global__ void k_bscan(const int* __restrict__ bsum, int* __restrict__ boff) {
    __shared__ int s[512];
    int t = threadIdx.x;
    int v = (t < NB) ? bsum[t] : 0;
    s[t] = v;
    __syncthreads();
    for (int off = 1; off < 512; off <<= 1) {
        int add = (t >= off) ? s[t - off] : 0;
        __syncthreads();
        s[t] += add;
        __syncthreads();
    }
    if (t < NB) boff[t] = s[t] - v;  // exclusive
}

// rowptr[i] = boff[block] + exclusive_scan_within_block(deg)
__global__ void k_rowptr(const int* __restrict__ deg, const int* __restrict__ boff,
                         int* __restrict__ rowptr) {
    __shared__ int s[256];
    int t = threadIdx.x;
    int i = blockIdx.x * 256 + t;
    int v = (i < NN) ? deg[i] : 0;
    s[t] = v;
    __syncthreads();
    for (int off = 1; off < 256; off <<= 1) {
        int add = (t >= off) ? s[t - off] : 0;
        __syncthreads();
        s[t] += add;
        __syncthreads();
    }
    if (i < NN) rowptr[i] = boff[blockIdx.x] + s[t] - v;
}

// scatter edge sources into CSR slots (4 edges/thread)
__global__ void k_fill(const int* __restrict__ ei, const int* __restrict__ rowptr,
                       int* __restrict__ cur, int* __restrict__ csr) {
    int e4 = blockIdx.x * blockDim.x + threadIdx.x;
    if (e4 * 4 >= NE) return;
    int4 r = ((const int4*)ei)[e4];
    int4 c = ((const int4*)(ei + NE))[e4];
    int p;
    p = atomicAdd(&cur[c.x], 1); csr[rowptr[c.x] + p] = r.x;
    p = atomicAdd(&cur[c.y], 1); csr[rowptr[c.y] + p] = r.y;
    p = atomicAdd(&cur[c.z], 1); csr[rowptr[c.z] + p] = r.z;
    p = atomicAdd(&cur[c.w], 1); csr[rowptr[c.w] + p] = r.w;
}

// xt = x @ W_gcn ; x row staged in LDS, W in LDS
__global__ void __launch_bounds__(256) k_xt(const float* __restrict__ x,
                                            const float* __restrict__ W,
                                            float* __restrict__ xt) {
    __shared__ float Wl[FIN * HH];  // 32 KB
    __shared__ float xs[4][FIN];    // 2 KB
    for (int t = threadIdx.x; t < FIN * HH; t += 256) Wl[t] = W[t];
    __syncthreads();
    int lane = threadIdx.x & 63;
    int w    = threadIdx.x >> 6;
    for (int row = blockIdx.x * 4 + w; row < NN; row += gridDim.x * 4) {
        float2 v = ((const float2*)(x + (size_t)row * FIN))[lane];
        xs[w][2 * lane]     = v.x;     // per-wave LDS, wave-synchronous
        xs[w][2 * lane + 1] = v.y;
        float acc = 0.f;
#pragma unroll
        for (int k = 0; k < FIN; ++k) acc = fmaf(xs[w][k], Wl[k * HH + lane], acc);
        xt[(size_t)row * HH + lane] = acc;
    }
}

// gather v2: wave per node; lane = (edge-phase r, feat-quad q); 4 edges in
// flight via dwordx4; shuffle-xor reduce across phases.
__global__ void __launch_bounds__(256) k_gather(const int* __restrict__ csr,
                                                const int* __restrict__ rowptr,
                                                const int* __restrict__ deg,
                                                const float* __restrict__ dis,
                                                const float* __restrict__ xt,
                                                const float* __restrict__ bg,
                                                float* __restrict__ g) {
    __shared__ int   lid[4][64];
    __shared__ float ldi[4][64];
    int t    = threadIdx.x;
    int lane = t & 63;
    int w    = t >> 6;
    int n    = blockIdx.x * 4 + w;
    if (n >= NN) return;
    int r = lane >> 4;   // edge phase 0..3
    int q = lane & 15;   // feature quad
    float4 acc = make_float4(0.f, 0.f, 0.f, 0.f);
    float dn  = dis[n];
    int start = rowptr[n];
    int cnt   = deg[n];
    for (int c0 = 0; c0 < cnt; c0 += 64) {
        int m = min(64, cnt - c0);
        if (lane < m) {
            int id = csr[start + c0 + lane];
            lid[w][lane] = id;          // per-wave slot, wave-synchronous
            ldi[w][lane] = dis[id];
        }
        for (int i = r; i < m; i += 4) {
            int   src = lid[w][i];
            float d   = ldi[w][i];
            float4 v = ((const float4*)(xt + (size_t)src * HH))[q];
            acc.x = fmaf(d, v.x, acc.x);
            acc.y = fmaf(d, v.y, acc.y);
            acc.z = fmaf(d, v.z, acc.z);
            acc.w = fmaf(d, v.w, acc.w);
        }
    }
    // reduce across the 4 phases (lane bits 4,5)
    acc.x += __shfl_xor(acc.x, 16, 64); acc.y += __shfl_xor(acc.y, 16, 64);
    acc.z += __shfl_xor(acc.z, 16, 64); acc.w += __shfl_xor(acc.w, 16, 64);
    acc.x += __shfl_xor(acc.x, 32, 64); acc.y += __shfl_xor(acc.y, 32, 64);
    acc.z += __shfl_xor(acc.z, 32, 64); acc.w += __shfl_xor(acc.w, 32, 64);

    float4 xs = ((const float4*)(xt + (size_t)n * HH))[q];
    float4 bb = ((const float4*)bg)[q];
    float4 res;
    res.x = fmaxf(fmaf(dn, fmaf(dn, xs.x, acc.x), bb.x), 0.f);
    res.y = fmaxf(fmaf(dn, fmaf(dn, xs.y, acc.y), bb.y), 0.f);
    res.z = fmaxf(fmaf(dn, fmaf(dn, xs.z, acc.z), bb.z), 0.f);
    res.w = fmaxf(fmaf(dn, fmaf(dn, xs.w, acc.w), bb.w), 0.f);
    if (r == 0) ((float4*)(g + (size_t)n * HH))[q] = res;
}

// GRU v3: 64 nodes/block; g/h transposed in LDS (stride 65 = conflict-free
// both ways, immediate offsets); thread=(node, j-quarter), g in registers,
// h from LDS; results written in place into Gt, then coalesced stores.
__global__ void __launch_bounds__(256, 4) k_gru(
    const float* __restrict__ gbuf, const float* __restrict__ hprev,
    const float* __restrict__ Wih, const float* __restrict__ Whh,
    const float* __restrict__ bih, const float* __restrict__ bhh,
    float* __restrict__ out) {
    __shared__ float Gt[64 * 65];  // 16.64 KB  [k][n] transposed, +1 pad
    __shared__ float Ht[64 * 65];  // 16.64 KB
    int t  = threadIdx.x;
    int n0 = blockIdx.x * 64;

    // stage: coalesced global -> transposed LDS
    for (int s = 0; s < 16; ++s) {
        int flat = t + 256 * s;            // node-major over 64 nodes x 64 feats
        int node = flat >> 6;              // wave-uniform
        int k    = flat & 63;
        size_t gi = (size_t)n0 * HH + flat;
        bool ok = (n0 + node) < NN;
        Gt[k * 65 + node] = ok ? gbuf[gi]  : 0.f;
        Ht[k * 65 + node] = ok ? hprev[gi] : 0.f;
    }
    __syncthreads();

    int nn = t & 63;   // node within block (= lane)
    int jq = t >> 6;   // j-quarter 0..3

    float g[HH];
#pragma unroll
    for (int k = 0; k < HH; ++k) g[k] = Gt[k * 65 + nn];
    __syncthreads();   // all g-loads done before Gt is overwritten with results

#pragma unroll 1
    for (int jj = 0; jj < 16; ++jj) {
        int j = jq * 16 + jj;              // wave-uniform -> weights via s_load
        float ir = bih[j], iz = bih[j + HH], in_ = bih[j + 2 * HH];
        float hr_ = bhh[j], hz = bhh[j + HH], hn = bhh[j + 2 * HH];
        const float* wi0 = Wih + (size_t)j * HH;
        const float* wi1 = Wih + (size_t)(j + HH) * HH;
        const float* wi2 = Wih + (size_t)(j + 2 * HH) * HH;
        const float* wh0 = Whh + (size_t)j * HH;
        const float* wh1 = Whh + (size_t)(j + HH) * HH;
        const float* wh2 = Whh + (size_t)(j + 2 * HH) * HH;
#pragma unroll
        for (int k = 0; k < HH; ++k) {
            float hk = Ht[k * 65 + nn];    // ds_read, conflict-free
            ir  = fmaf(wi0[k], g[k], ir);
            iz  = fmaf(wi1[k], g[k], iz);
            in_ = fmaf(wi2[k], g[k], in_);
            hr_ = fmaf(wh0[k], hk, hr_);
            hz  = fmaf(wh1[k], hk, hz);
            hn  = fmaf(wh2[k], hk, hn);
        }
        float r  = __builtin_amdgcn_rcpf(1.f + __expf(-(ir + hr_)));
        float z  = __builtin_amdgcn_rcpf(1.f + __expf(-(iz + hz)));
        float e2 = __expf(2.f * fmaf(r, hn, in_));
        float nv = fmaf(-2.f, __builtin_amdgcn_rcpf(1.f + e2), 1.f);  // tanh
        float hj = Ht[j * 65 + nn];
        Gt[j * 65 + nn] = (1.f - z) * nv + z * hj;
    }
    __syncthreads();

    // epilogue: transposed LDS -> coalesced global, written twice
    for (int s = 0; s < 16; ++s) {
        int flat = t + 256 * s;
        int node = flat >> 6;
        int j    = flat & 63;
        if (n0 + node < NN) {
            float v = Gt[j * 65 + node];
            out[(size_t)n0 * HH + flat] = v;
            out[(size_t)NN * HH + (size_t)n0 * HH + flat] = v;
        }
    }
}

extern "C" void kernel_launch(void* const* d_in, const int* in_sizes, int n_in,
                              void* d_out, int out_size, void* d_ws, size_t ws_size,
                              hipStream_t stream) {
    const float* x   = (const float*)d_in[0];
    const int*   ei  = (const int*)d_in[1];
    const float* hs  = (const float*)d_in[2];
    const float* Wg  = (const float*)d_in[3];
    const float* bg  = (const float*)d_in[4];
    const float* Wih = (const float*)d_in[5];
    const float* Whh = (const float*)d_in[6];
    const float* bih = (const float*)d_in[7];
    const float* bhh = (const float*)d_in[8];
    float* out = (float*)d_out;

    char* ws = (char*)d_ws;
    float* xt     = (float*)(ws);                  // 25,600,000 B
    float* gbuf   = (float*)(ws + 25600000);       // 25,600,000 B
    int*   csr    = (int*)  (ws + 51200000);       // 12,800,000 B
    int*   deg    = (int*)  (ws + 64000000);       //    400,000 B
    int*   rowptr = (int*)  (ws + 64400000);       //    400,000 B
    int*   cur    = (int*)  (ws + 64800000);       //    400,000 B
    float* dis    = (float*)(ws + 65200000);       //    400,000 B
    int*   bsum   = (int*)  (ws + 65600000);       //      2,048 B
    int*   boff   = (int*)  (ws + 65604096);       //      2,048 B

    hipMemsetAsync(deg, 0, NN * sizeof(int), stream);
    hipMemsetAsync(cur, 0, NN * sizeof(int), stream);

    hipLaunchKernelGGL(k_count,  dim3((NE / 4 + 255) / 256), dim3(256), 0, stream, ei + NE, deg);
    hipLaunchKernelGGL(k_dis,    dim3((NN + 255) / 256), dim3(256), 0, stream, deg, dis);
    hipLaunchKernelGGL(k_bsum,   dim3(NB), dim3(256), 0, stream, deg, bsum);
    hipLaunchKernelGGL(k_bscan,  dim3(1), dim3(512), 0, stream, bsum, boff);
    hipLaunchKernelGGL(k_rowptr, dim3(NB), dim3(256), 0, stream, deg, boff, rowptr);
    hipLaunchKernelGGL(k_fill,   dim3((NE / 4 + 255) / 256), dim3(256), 0, stream, ei, rowptr, cur, csr);
    hipLaunchKernelGGL(k_xt,     dim3(2048), dim3(256), 0, stream, x, Wg, xt);
    hipLaunchKernelGGL(k_gather, dim3((NN + 3) / 4), dim3(256), 0, stream,
                       csr, rowptr, deg, dis, xt, bg, gbuf);
    hipLaunchKernelGGL(k_gru,    dim3((NN + 63) / 64), dim3(256), 0, stream,
                       gbuf, hs, Wih, Whh, bih, bhh, out);
}

// Round 5
// 1029.917 us; speedup vs baseline: 2.2777x; 2.2777x over previous
//
#include <hip/hip_runtime.h>
#include <cmath>

constexpr int NN  = 100000;
constexpr int FIN = 128;
constexpr int HH  = 64;
constexpr int NE  = 3200000;
constexpr int NB  = (NN + 255) / 256;  // 391 scan blocks

// deg[col[e]] += 1  (4 edges/thread; NE % 4 == 0)
__global__ void k_count(const int* __restrict__ col, int* __restrict__ deg) {
    int e4 = blockIdx.x * blockDim.x + threadIdx.x;
    if (e4 * 4 < NE) {
        int4 c = ((const int4*)col)[e4];
        atomicAdd(&deg[c.x], 1);
        atomicAdd(&deg[c.y], 1);
        atomicAdd(&deg[c.z], 1);
        atomicAdd(&deg[c.w], 1);
    }
}

// dis[i] = rsqrt(deg[i] + 1)
__global__ void k_dis(const int* __restrict__ deg, float* __restrict__ dis) {
    int i = blockIdx.x * blockDim.x + threadIdx.x;
    if (i < NN) dis[i] = rsqrtf((float)(deg[i] + 1));
}

// per-256-chunk sums of deg
__global__ void k_bsum(const int* __restrict__ deg, int* __restrict__ bsum) {
    __shared__ int s[256];
    int i = blockIdx.x * 256 + threadIdx.x;
    s[threadIdx.x] = (i < NN) ? deg[i] : 0;
    __syncthreads();
    for (int off = 128; off > 0; off >>= 1) {
        if (threadIdx.x < off) s[threadIdx.x] += s[threadIdx.x + off];
        __syncthreads();
    }
    if (threadIdx.x == 0) bsum[blockIdx.x] = s[0];
}

// exclusive scan of the NB block sums (single block, Hillis-Steele over 512)
__global__ void k_bscan(const int* __restrict__ bsum, int* __restrict__ boff) {
    __shared__ int s[512];
    int t = threadIdx.x;
    int v = (t < NB) ? bsum[t] : 0;
    s[t] = v;
    __syncthreads();
    for (int off = 1; off < 512; off <<= 1) {
        int add = (t >= off) ? s[t - off] : 0;
        __syncthreads();
        s[t] += add;
        __syncthreads();
    }
    if (t < NB) boff[t] = s[t] - v;  // exclusive
}

// rowptr[i] = boff[block] + exclusive_scan_within_block(deg)
__global__ void k_rowptr(const int* __restrict__ deg, const int* __restrict__ boff,
                         int* __restrict__ rowptr) {
    __shared__ int s[256];
    int t = threadIdx.x;
    int i = blockIdx.x * 256 + t;
    int v = (i < NN) ? deg[i] : 0;
    s[t] = v;
    __syncthreads();
    for (int off = 1; off < 256; off <<= 1) {
        int add = (t >= off) ? s[t - off] : 0;
        __syncthreads();
        s[t] += add;
        __syncthreads();
    }
    if (i < NN) rowptr[i] = boff[blockIdx.x] + s[t] - v;
}

// scatter edge sources into CSR slots (4 edges/thread)
__global__ void k_fill(const int* __restrict__ ei, const int* __restrict__ rowptr,
                       int* __restrict__ cur, int* __restrict__ csr) {
    int e4 = blockIdx.x * blockDim.x + threadIdx.x;
    if (e4 * 4 >= NE) return;
    int4 r = ((const int4*)ei)[e4];
    int4 c = ((const int4*)(ei + NE))[e4];
    int p;
    p = atomicAdd(&cur[c.x], 1); csr[rowptr[c.x] + p] = r.x;
    p = atomicAdd(&cur[c.y], 1); csr[rowptr[c.y] + p] = r.y;
    p = atomicAdd(&cur[c.z], 1); csr[rowptr[c.z] + p] = r.z;
    p = atomicAdd(&cur[c.w], 1); csr[rowptr[c.w] + p] = r.w;
}

// xt = x @ W_gcn ; x row staged in LDS, W in LDS
__global__ void __launch_bounds__(256) k_xt(const float* __restrict__ x,
                                            const float* __restrict__ W,
                                            float* __restrict__ xt) {
    __shared__ float Wl[FIN * HH];  // 32 KB
    __shared__ float xs[4][FIN];    // 2 KB
    for (int t = threadIdx.x; t < FIN * HH; t += 256) Wl[t] = W[t];
    __syncthreads();
    int lane = threadIdx.x & 63;
    int w    = threadIdx.x >> 6;
    for (int row = blockIdx.x * 4 + w; row < NN; row += gridDim.x * 4) {
        float2 v = ((const float2*)(x + (size_t)row * FIN))[lane];
        xs[w][2 * lane]     = v.x;     // per-wave LDS, wave-synchronous
        xs[w][2 * lane + 1] = v.y;
        float acc = 0.f;
#pragma unroll
        for (int k = 0; k < FIN; ++k) acc = fmaf(xs[w][k], Wl[k * HH + lane], acc);
        xt[(size_t)row * HH + lane] = acc;
    }
}

// gather v2: wave per node; lane = (edge-phase r, feat-quad q); 4 edges in
// flight via dwordx4; shuffle-xor reduce across phases.
__global__ void __launch_bounds__(256) k_gather(const int* __restrict__ csr,
                                                const int* __restrict__ rowptr,
                                                const int* __restrict__ deg,
                                                const float* __restrict__ dis,
                                                const float* __restrict__ xt,
                                                const float* __restrict__ bg,
                                                float* __restrict__ g) {
    __shared__ int   lid[4][64];
    __shared__ float ldi[4][64];
    int t    = threadIdx.x;
    int lane = t & 63;
    int w    = t >> 6;
    int n    = blockIdx.x * 4 + w;
    if (n >= NN) return;
    int r = lane >> 4;   // edge phase 0..3
    int q = lane & 15;   // feature quad
    float4 acc = make_float4(0.f, 0.f, 0.f, 0.f);
    float dn  = dis[n];
    int start = rowptr[n];
    int cnt   = deg[n];
    for (int c0 = 0; c0 < cnt; c0 += 64) {
        int m = min(64, cnt - c0);
        if (lane < m) {
            int id = csr[start + c0 + lane];
            lid[w][lane] = id;          // per-wave slot, wave-synchronous
            ldi[w][lane] = dis[id];
        }
        for (int i = r; i < m; i += 4) {
            int   src = lid[w][i];
            float d   = ldi[w][i];
            float4 v = ((const float4*)(xt + (size_t)src * HH))[q];
            acc.x = fmaf(d, v.x, acc.x);
            acc.y = fmaf(d, v.y, acc.y);
            acc.z = fmaf(d, v.z, acc.z);
            acc.w = fmaf(d, v.w, acc.w);
        }
    }
    // reduce across the 4 phases (lane bits 4,5)
    acc.x += __shfl_xor(acc.x, 16, 64); acc.y += __shfl_xor(acc.y, 16, 64);
    acc.z += __shfl_xor(acc.z, 16, 64); acc.w += __shfl_xor(acc.w, 16, 64);
    acc.x += __shfl_xor(acc.x, 32, 64); acc.y += __shfl_xor(acc.y, 32, 64);
    acc.z += __shfl_xor(acc.z, 32, 64); acc.w += __shfl_xor(acc.w, 32, 64);

    float4 xs = ((const float4*)(xt + (size_t)n * HH))[q];
    float4 bb = ((const float4*)bg)[q];
    float4 res;
    res.x = fmaxf(fmaf(dn, fmaf(dn, xs.x, acc.x), bb.x), 0.f);
    res.y = fmaxf(fmaf(dn, fmaf(dn, xs.y, acc.y), bb.y), 0.f);
    res.z = fmaxf(fmaf(dn, fmaf(dn, xs.z, acc.z), bb.z), 0.f);
    res.w = fmaxf(fmaf(dn, fmaf(dn, xs.w, acc.w), bb.w), 0.f);
    if (r == 0) ((float4*)(g + (size_t)n * HH))[q] = res;
}

// GRU v5: 64 nodes/block, thread=(node, j-quarter). NO per-thread arrays —
// g and h both read from LDS per-k as an adjacent dword pair (ds_read2-able,
// banks (4k+node)%32 = 2-way free). 4 accumulators/j. Results via LDS ->
// coalesced full-line stores. ~48 VGPR, no spill possible.
__global__ void __launch_bounds__(256) k_gru(
    const float* __restrict__ gbuf, const float* __restrict__ hprev,
    const float* __restrict__ Wih, const float* __restrict__ Whh,
    const float* __restrict__ bih, const float* __restrict__ bhh,
    float* __restrict__ out) {
    __shared__ float GH[64 * 132];  // [k][ g:+node | h:+66+node ], 33.8 KB
    __shared__ float Rt[64 * 67];   // [j][node] results, 17.2 KB
    int t  = threadIdx.x;
    int n0 = blockIdx.x * 64;

    // stage: coalesced global -> LDS (g and h interleaved by k-row)
    for (int s = 0; s < 16; ++s) {
        int flat = t + 256 * s;            // node-major over 64 nodes x 64 feats
        int node = flat >> 6;
        int k    = flat & 63;
        bool ok  = (n0 + node) < NN;
        size_t gi = (size_t)n0 * HH + flat;
        GH[k * 132 + node]      = ok ? gbuf[gi]  : 0.f;
        GH[k * 132 + 66 + node] = ok ? hprev[gi] : 0.f;
    }
    __syncthreads();

    int node = t & 63;
    int jq   = t >> 6;   // wave-uniform
#pragma unroll 1
    for (int jj = 0; jj < 16; ++jj) {
        int j = jq * 16 + jj;              // wave-uniform -> weights via s_load
        float ar = bih[j]       + bhh[j];        // r-gate presum
        float az = bih[j + HH]  + bhh[j + HH];   // z-gate presum
        float an = bih[j + 2 * HH];
        float ah = bhh[j + 2 * HH];
        const float* wi0 = Wih + (size_t)j * HH;
        const float* wi1 = Wih + (size_t)(j + HH) * HH;
        const float* wi2 = Wih + (size_t)(j + 2 * HH) * HH;
        const float* wh0 = Whh + (size_t)j * HH;
        const float* wh1 = Whh + (size_t)(j + HH) * HH;
        const float* wh2 = Whh + (size_t)(j + 2 * HH) * HH;
#pragma unroll
        for (int k = 0; k < HH; ++k) {
            float gk = GH[k * 132 + node];
            float hk = GH[k * 132 + 66 + node];
            ar = fmaf(wi0[k], gk, fmaf(wh0[k], hk, ar));
            az = fmaf(wi1[k], gk, fmaf(wh1[k], hk, az));
            an = fmaf(wi2[k], gk, an);
            ah = fmaf(wh2[k], hk, ah);
        }
        float r  = __builtin_amdgcn_rcpf(1.f + __expf(-ar));
        float z  = __builtin_amdgcn_rcpf(1.f + __expf(-az));
        float e2 = __expf(2.f * fmaf(r, ah, an));
        float nv = fmaf(-2.f, __builtin_amdgcn_rcpf(1.f + e2), 1.f);  // tanh
        float hj = GH[j * 132 + 66 + node];
        Rt[j * 67 + node] = (1.f - z) * nv + z * hj;
    }
    __syncthreads();

    // epilogue: LDS -> coalesced global, full lines, written twice
    for (int s = 0; s < 16; ++s) {
        int flat = t + 256 * s;
        int nd = flat >> 6;
        int j  = flat & 63;
        if (n0 + nd < NN) {
            float v = Rt[j * 67 + nd];
            out[(size_t)n0 * HH + flat] = v;
            out[(size_t)NN * HH + (size_t)n0 * HH + flat] = v;
        }
    }
}

extern "C" void kernel_launch(void* const* d_in, const int* in_sizes, int n_in,
                              void* d_out, int out_size, void* d_ws, size_t ws_size,
                              hipStream_t stream) {
    const float* x   = (const float*)d_in[0];
    const int*   ei  = (const int*)d_in[1];
    const float* hs  = (const float*)d_in[2];
    const float* Wg  = (const float*)d_in[3];
    const float* bg  = (const float*)d_in[4];
    const float* Wih = (const float*)d_in[5];
    const float* Whh = (const float*)d_in[6];
    const float* bih = (const float*)d_in[7];
    const float* bhh = (const float*)d_in[8];
    float* out = (float*)d_out;

    char* ws = (char*)d_ws;
    float* xt     = (float*)(ws);                  // 25,600,000 B
    float* gbuf   = (float*)(ws + 25600000);       // 25,600,000 B
    int*   csr    = (int*)  (ws + 51200000);       // 12,800,000 B
    int*   deg    = (int*)  (ws + 64000000);       //    400,000 B
    int*   rowptr = (int*)  (ws + 64400000);       //    400,000 B
    int*   cur    = (int*)  (ws + 64800000);       //    400,000 B
    float* dis    = (float*)(ws + 65200000);       //    400,000 B
    int*   bsum   = (int*)  (ws + 65600000);       //      2,048 B
    int*   boff   = (int*)  (ws + 65604096);       //      2,048 B

    hipMemsetAsync(deg, 0, NN * sizeof(int), stream);
    hipMemsetAsync(cur, 0, NN * sizeof(int), stream);

    hipLaunchKernelGGL(k_count,  dim3((NE / 4 + 255) / 256), dim3(256), 0, stream, ei + NE, deg);
    hipLaunchKernelGGL(k_dis,    dim3((NN + 255) / 256), dim3(256), 0, stream, deg, dis);
    hipLaunchKernelGGL(k_bsum,   dim3(NB), dim3(256), 0, stream, deg, bsum);
    hipLaunchKernelGGL(k_bscan,  dim3(1), dim3(512), 0, stream, bsum, boff);
    hipLaunchKernelGGL(k_rowptr, dim3(NB), dim3(256), 0, stream, deg, boff, rowptr);
    hipLaunchKernelGGL(k_fill,   dim3((NE / 4 + 255) / 256), dim3(256), 0, stream, ei, rowptr, cur, csr);
    hipLaunchKernelGGL(k_xt,     dim3(2048), dim3(256), 0, stream, x, Wg, xt);
    hipLaunchKernelGGL(k_gather, dim3((NN + 3) / 4), dim3(256), 0, stream,
                       csr, rowptr, deg, dis, xt, bg, gbuf);
    hipLaunchKernelGGL(k_gru,    dim3((NN + 63) / 64), dim3(256), 0, stream,
                       gbuf, hs, Wih, Whh, bih, bhh, out);
}

// Round 6
// 919.809 us; speedup vs baseline: 2.5504x; 1.1197x over previous
//
#include <hip/hip_runtime.h>
#include <cmath>

constexpr int NN  = 100000;
constexpr int FIN = 128;
constexpr int HH  = 64;
constexpr int NE  = 3200000;
constexpr int NB  = (NN + 255) / 256;  // 391 scan blocks

// deg[col[e]] += 1  (4 edges/thread; NE % 4 == 0)
__global__ void k_count(const int* __restrict__ col, int* __restrict__ deg) {
    int e4 = blockIdx.x * blockDim.x + threadIdx.x;
    if (e4 * 4 < NE) {
        int4 c = ((const int4*)col)[e4];
        atomicAdd(&deg[c.x], 1);
        atomicAdd(&deg[c.y], 1);
        atomicAdd(&deg[c.z], 1);
        atomicAdd(&deg[c.w], 1);
    }
}

// dis[i] = rsqrt(deg[i] + 1)
__global__ void k_dis(const int* __restrict__ deg, float* __restrict__ dis) {
    int i = blockIdx.x * blockDim.x + threadIdx.x;
    if (i < NN) dis[i] = rsqrtf((float)(deg[i] + 1));
}

// per-256-chunk sums of deg
__global__ void k_bsum(const int* __restrict__ deg, int* __restrict__ bsum) {
    __shared__ int s[256];
    int i = blockIdx.x * 256 + threadIdx.x;
    s[threadIdx.x] = (i < NN) ? deg[i] : 0;
    __syncthreads();
    for (int off = 128; off > 0; off >>= 1) {
        if (threadIdx.x < off) s[threadIdx.x] += s[threadIdx.x + off];
        __syncthreads();
    }
    if (threadIdx.x == 0) bsum[blockIdx.x] = s[0];
}

// exclusive scan of the NB block sums (single block, Hillis-Steele over 512)
__global__ void k_bscan(const int* __restrict__ bsum, int* __restrict__ boff) {
    __shared__ int s[512];
    int t = threadIdx.x;
    int v = (t < NB) ? bsum[t] : 0;
    s[t] = v;
    __syncthreads();
    for (int off = 1; off < 512; off <<= 1) {
        int add = (t >= off) ? s[t - off] : 0;
        __syncthreads();
        s[t] += add;
        __syncthreads();
    }
    if (t < NB) boff[t] = s[t] - v;  // exclusive
}

// rowptr[i] = boff[block] + exclusive_scan_within_block(deg)
__global__ void k_rowptr(const int* __restrict__ deg, const int* __restrict__ boff,
                         int* __restrict__ rowptr) {
    __shared__ int s[256];
    int t = threadIdx.x;
    int i = blockIdx.x * 256 + t;
    int v = (i < NN) ? deg[i] : 0;
    s[t] = v;
    __syncthreads();
    for (int off = 1; off < 256; off <<= 1) {
        int add = (t >= off) ? s[t - off] : 0;
        __syncthreads();
        s[t] += add;
        __syncthreads();
    }
    if (i < NN) rowptr[i] = boff[blockIdx.x] + s[t] - v;
}

// scatter edge sources into CSR slots (4 edges/thread)
__global__ void k_fill(const int* __restrict__ ei, const int* __restrict__ rowptr,
                       int* __restrict__ cur, int* __restrict__ csr) {
    int e4 = blockIdx.x * blockDim.x + threadIdx.x;
    if (e4 * 4 >= NE) return;
    int4 r = ((const int4*)ei)[e4];
    int4 c = ((const int4*)(ei + NE))[e4];
    int p;
    p = atomicAdd(&cur[c.x], 1); csr[rowptr[c.x] + p] = r.x;
    p = atomicAdd(&cur[c.y], 1); csr[rowptr[c.y] + p] = r.y;
    p = atomicAdd(&cur[c.z], 1); csr[rowptr[c.z] + p] = r.z;
    p = atomicAdd(&cur[c.w], 1); csr[rowptr[c.w] + p] = r.w;
}

// xt v3 = x @ W_gcn. Wave w holds W[k=32w..32w+31][lane] in 32 VGPRs.
// x-row elements are wave-uniform -> scalar s_load broadcasts. Partials
// through LDS, 16 rows per phase. Inner loop: 1 v_fmac per element, no LDS.
__global__ void __launch_bounds__(256) k_xt(const float* __restrict__ x,
                                            const float* __restrict__ W,
                                            float* __restrict__ xt) {
    __shared__ float part[16 * 256];  // [row][w*64+lane], 16 KB
    int t    = threadIdx.x;
    int lane = t & 63;
    int kbase = __builtin_amdgcn_readfirstlane((t >> 6) * 32);  // uniform
    float wreg[32];
#pragma unroll
    for (int kk = 0; kk < 32; ++kk) wreg[kk] = W[(kbase + kk) * HH + lane];

    // 100000 = 6250 phases * 16 rows exactly
    for (int ph = blockIdx.x; ph < 6250; ph += gridDim.x) {
        int rowBase = ph * 16;
#pragma unroll 2
        for (int r = 0; r < 16; ++r) {
            const float* xr = x + (size_t)(rowBase + r) * FIN + kbase;  // uniform addr
            float acc = 0.f;
#pragma unroll
            for (int kk = 0; kk < 32; ++kk) acc = fmaf(xr[kk], wreg[kk], acc);
            part[r * 256 + (kbase << 1) + lane] = acc;  // (kbase/32)*64 + lane
        }
        __syncthreads();
#pragma unroll
        for (int rr = 0; rr < 4; ++rr) {
            int f = t + 256 * rr;          // 0..1023 = (row, col)
            int r = f >> 6, l = f & 63;
            float s = part[r * 256 + l] + part[r * 256 + 64 + l]
                    + part[r * 256 + 128 + l] + part[r * 256 + 192 + l];
            xt[(size_t)rowBase * HH + f] = s;
        }
        __syncthreads();
    }
}

// gather v2: wave per node; lane = (edge-phase r, feat-quad q); 4 edges in
// flight via dwordx4; shuffle-xor reduce across phases.
__global__ void __launch_bounds__(256) k_gather(const int* __restrict__ csr,
                                                const int* __restrict__ rowptr,
                                                const int* __restrict__ deg,
                                                const float* __restrict__ dis,
                                                const float* __restrict__ xt,
                                                const float* __restrict__ bg,
                                                float* __restrict__ g) {
    __shared__ int   lid[4][64];
    __shared__ float ldi[4][64];
    int t    = threadIdx.x;
    int lane = t & 63;
    int w    = t >> 6;
    int n    = blockIdx.x * 4 + w;
    if (n >= NN) return;
    int r = lane >> 4;   // edge phase 0..3
    int q = lane & 15;   // feature quad
    float4 acc = make_float4(0.f, 0.f, 0.f, 0.f);
    float dn  = dis[n];
    int start = rowptr[n];
    int cnt   = deg[n];
    for (int c0 = 0; c0 < cnt; c0 += 64) {
        int m = min(64, cnt - c0);
        if (lane < m) {
            int id = csr[start + c0 + lane];
            lid[w][lane] = id;          // per-wave slot, wave-synchronous
            ldi[w][lane] = dis[id];
        }
        for (int i = r; i < m; i += 4) {
            int   src = lid[w][i];
            float d   = ldi[w][i];
            float4 v = ((const float4*)(xt + (size_t)src * HH))[q];
            acc.x = fmaf(d, v.x, acc.x);
            acc.y = fmaf(d, v.y, acc.y);
            acc.z = fmaf(d, v.z, acc.z);
            acc.w = fmaf(d, v.w, acc.w);
        }
    }
    // reduce across the 4 phases (lane bits 4,5)
    acc.x += __shfl_xor(acc.x, 16, 64); acc.y += __shfl_xor(acc.y, 16, 64);
    acc.z += __shfl_xor(acc.z, 16, 64); acc.w += __shfl_xor(acc.w, 16, 64);
    acc.x += __shfl_xor(acc.x, 32, 64); acc.y += __shfl_xor(acc.y, 32, 64);
    acc.z += __shfl_xor(acc.z, 32, 64); acc.w += __shfl_xor(acc.w, 32, 64);

    float4 xs = ((const float4*)(xt + (size_t)n * HH))[q];
    float4 bb = ((const float4*)bg)[q];
    float4 res;
    res.x = fmaxf(fmaf(dn, fmaf(dn, xs.x, acc.x), bb.x), 0.f);
    res.y = fmaxf(fmaf(dn, fmaf(dn, xs.y, acc.y), bb.y), 0.f);
    res.z = fmaxf(fmaf(dn, fmaf(dn, xs.z, acc.z), bb.z), 0.f);
    res.w = fmaxf(fmaf(dn, fmaf(dn, xs.w, acc.w), bb.w), 0.f);
    if (r == 0) ((float4*)(g + (size_t)n * HH))[q] = res;
}

// GRU v6: 64 nodes/block, thread=(node, jq). k tiled by 16: g/h cached in 32
// VGPRs, applied to all 16 j accumulators (64 accums, constant-indexed).
// jq via readfirstlane -> weight loads are uniform -> s_load broadcasts.
// Results in-place into GH g-slots (barrier-protected), coalesced stores.
__global__ void __launch_bounds__(256) k_gru(
    const float* __restrict__ gbuf, const float* __restrict__ hprev,
    const float* __restrict__ Wih, const float* __restrict__ Whh,
    const float* __restrict__ bih, const float* __restrict__ bhh,
    float* __restrict__ out) {
    __shared__ float GH[64 * 132];  // [k][ g:+node | h:+66+node ], 33.8 KB
    int t  = threadIdx.x;
    int n0 = blockIdx.x * 64;

    // stage: coalesced global -> LDS
    for (int s = 0; s < 16; ++s) {
        int flat = t + 256 * s;
        int node = flat >> 6;
        int k    = flat & 63;
        bool ok  = (n0 + node) < NN;
        size_t gi = (size_t)n0 * HH + flat;
        GH[k * 132 + node]      = ok ? gbuf[gi]  : 0.f;
        GH[k * 132 + 66 + node] = ok ? hprev[gi] : 0.f;
    }
    __syncthreads();

    int node = t & 63;
    int jq   = __builtin_amdgcn_readfirstlane(t >> 6);  // provably uniform

    float ar[16], az[16], an[16], ah[16];
#pragma unroll
    for (int jj = 0; jj < 16; ++jj) {
        int j = jq * 16 + jj;
        ar[jj] = bih[j]          + bhh[j];
        az[jj] = bih[j + HH]     + bhh[j + HH];
        an[jj] = bih[j + 2 * HH];
        ah[jj] = bhh[j + 2 * HH];
    }

#pragma unroll 1
    for (int kt = 0; kt < HH; kt += 16) {
        float gk[16], hk[16];
#pragma unroll
        for (int kk = 0; kk < 16; ++kk) {
            gk[kk] = GH[(kt + kk) * 132 + node];
            hk[kk] = GH[(kt + kk) * 132 + 66 + node];
        }
#pragma unroll
        for (int jj = 0; jj < 16; ++jj) {
            int j = jq * 16 + jj;
            const float* wi0 = Wih + (size_t)j * HH + kt;
            const float* wi1 = Wih + (size_t)(j + HH) * HH + kt;
            const float* wi2 = Wih + (size_t)(j + 2 * HH) * HH + kt;
            const float* wh0 = Whh + (size_t)j * HH + kt;
            const float* wh1 = Whh + (size_t)(j + HH) * HH + kt;
            const float* wh2 = Whh + (size_t)(j + 2 * HH) * HH + kt;
#pragma unroll
            for (int kk = 0; kk < 16; ++kk) {
                ar[jj] = fmaf(wi0[kk], gk[kk], fmaf(wh0[kk], hk[kk], ar[jj]));
                az[jj] = fmaf(wi1[kk], gk[kk], fmaf(wh1[kk], hk[kk], az[jj]));
                an[jj] = fmaf(wi2[kk], gk[kk], an[jj]);
                ah[jj] = fmaf(wh2[kk], hk[kk], ah[jj]);
            }
        }
    }

    float res[16];
#pragma unroll
    for (int jj = 0; jj < 16; ++jj) {
        int j = jq * 16 + jj;
        float r  = __builtin_amdgcn_rcpf(1.f + __expf(-ar[jj]));
        float z  = __builtin_amdgcn_rcpf(1.f + __expf(-az[jj]));
        float e2 = __expf(2.f * fmaf(r, ah[jj], an[jj]));
        float nv = fmaf(-2.f, __builtin_amdgcn_rcpf(1.f + e2), 1.f);  // tanh
        float hj = GH[j * 132 + 66 + node];
        res[jj] = (1.f - z) * nv + z * hj;
    }
    __syncthreads();   // all reads of GH done
#pragma unroll
    for (int jj = 0; jj < 16; ++jj) GH[(jq * 16 + jj) * 132 + node] = res[jj];
    __syncthreads();

    // epilogue: LDS -> coalesced global, full lines, written twice
    for (int s = 0; s < 16; ++s) {
        int flat = t + 256 * s;
        int nd = flat >> 6;
        int j  = flat & 63;
        if (n0 + nd < NN) {
            float v = GH[j * 132 + nd];
            out[(size_t)n0 * HH + flat] = v;
            out[(size_t)NN * HH + (size_t)n0 * HH + flat] = v;
        }
    }
}

extern "C" void kernel_launch(void* const* d_in, const int* in_sizes, int n_in,
                              void* d_out, int out_size, void* d_ws, size_t ws_size,
                              hipStream_t stream) {
    const float* x   = (const float*)d_in[0];
    const int*   ei  = (const int*)d_in[1];
    const float* hs  = (const float*)d_in[2];
    const float* Wg  = (const float*)d_in[3];
    const float* bg  = (const float*)d_in[4];
    const float* Wih = (const float*)d_in[5];
    const float* Whh = (const float*)d_in[6];
    const float* bih = (const float*)d_in[7];
    const float* bhh = (const float*)d_in[8];
    float* out = (float*)d_out;

    char* ws = (char*)d_ws;
    float* xt     = (float*)(ws);                  // 25,600,000 B
    float* gbuf   = (float*)(ws + 25600000);       // 25,600,000 B
    int*   csr    = (int*)  (ws + 51200000);       // 12,800,000 B
    int*   deg    = (int*)  (ws + 64000000);       //    400,000 B
    int*   rowptr = (int*)  (ws + 64400000);       //    400,000 B
    int*   cur    = (int*)  (ws + 64800000);       //    400,000 B
    float* dis    = (float*)(ws + 65200000);       //    400,000 B
    int*   bsum   = (int*)  (ws + 65600000);       //      2,048 B
    int*   boff   = (int*)  (ws + 65604096);       //      2,048 B

    hipMemsetAsync(deg, 0, NN * sizeof(int), stream);
    hipMemsetAsync(cur, 0, NN * sizeof(int), stream);

    hipLaunchKernelGGL(k_count,  dim3((NE / 4 + 255) / 256), dim3(256), 0, stream, ei + NE, deg);
    hipLaunchKernelGGL(k_dis,    dim3((NN + 255) / 256), dim3(256), 0, stream, deg, dis);
    hipLaunchKernelGGL(k_bsum,   dim3(NB), dim3(256), 0, stream, deg, bsum);
    hipLaunchKernelGGL(k_bscan,  dim3(1), dim3(512), 0, stream, bsum, boff);
    hipLaunchKernelGGL(k_rowptr, dim3(NB), dim3(256), 0, stream, deg, boff, rowptr);
    hipLaunchKernelGGL(k_fill,   dim3((NE / 4 + 255) / 256), dim3(256), 0, stream, ei, rowptr, cur, csr);
    hipLaunchKernelGGL(k_xt,     dim3(1024), dim3(256), 0, stream, x, Wg, xt);
    hipLaunchKernelGGL(k_gather, dim3((NN + 3) / 4), dim3(256), 0, stream,
                       csr, rowptr, deg, dis, xt, bg, gbuf);
    hipLaunchKernelGGL(k_gru,    dim3((NN + 63) / 64), dim3(256), 0, stream,
                       gbuf, hs, Wih, Whh, bih, bhh, out);
}